// Round 4
// baseline (370.256 us; speedup 1.0000x reference)
//
#include <hip/hip_runtime.h>
#include <cstdint>
#include <cstddef>

typedef unsigned short u16;
typedef unsigned int u32;
typedef __bf16 bf16x8 __attribute__((ext_vector_type(8)));
typedef float f32x4 __attribute__((ext_vector_type(4)));

#define SL 2048            // sequence length
#define NCH 8192           // B(16) * BIDIR(2) * N_OUT(256)
#define SEGS 64

// out buffer element offsets (f32 output)
#define OFF_C2S 16777216
#define OFF_C1F 33554432
#define OFF_C2F 33562624
#define OFF_DF  33570816

__device__ __forceinline__ u16 f2bf(float f) {
  union { float f; u32 i; } v; v.f = f;
  u32 x = v.i;
  return (u16)((x + 0x7fffu + ((x >> 16) & 1u)) >> 16);
}
// pack two f32 -> two bf16 (RNE), 1 VALU op
__device__ __forceinline__ u32 cvtpk(float lo, float hi) {
  u32 r;
  asm("v_cvt_pk_bf16_f32 %0, %1, %2" : "=v"(r) : "v"(lo), "v"(hi));
  return r;
}
__device__ __forceinline__ float sigmoidf(float v) {
  return 1.f / (1.f + __expf(-v));
}

// -------------------------------------------------------------------------
// Convert x (f32 [t][b][256]) -> xb (bf16, layout [ot][kb(32)][b(16)][8])
// so GEMM A-fragment loads are wave-contiguous 1KB direct from global.
__global__ __launch_bounds__(256) void xconv_kernel(
    const float* __restrict__ x, u16* __restrict__ xb) {
  int t8 = blockIdx.x * 256 + threadIdx.x;    // < 1,048,576
  int kb = t8 & 31;
  int b  = (t8 >> 5) & 15;
  int ot = t8 >> 9;
  const float* src = x + (((size_t)(ot * 16 + b)) << 8) + kb * 8;
  f32x4 a = *(const f32x4*)src;
  f32x4 c = *(const f32x4*)(src + 4);
  union { bf16x8 v; u32 u[4]; } h;
  h.u[0] = cvtpk(a[0], a[1]);
  h.u[1] = cvtpk(a[2], a[3]);
  h.u[2] = cvtpk(c[0], c[1]);
  h.u[3] = cvtpk(c[2], c[3]);
  *(bf16x8*)(xb + ((size_t)ot << 12) + kb * 128 + b * 8) = h.v;
}

// -------------------------------------------------------------------------
// Repack weight_in (f32, 256 x 3072, col = dir*1536 + n*6 + k) into bf16 in
// MFMA-fragment order: fragment f = ((p*32+cg)*4+kt)*2+h holds, at
// [lane][kk8]: ch2 = cg*16 + (lane&15), kk = (kt*8+h*4+(lane>>4))*8 + kk8.
__global__ __launch_bounds__(256) void repack_kernel(
    const float* __restrict__ W, u16* __restrict__ Wt) {
  int idx = blockIdx.x * 256 + threadIdx.x;   // < 5*512*256 = 655360
  int kk8 = idx & 7;
  int lane = (idx >> 3) & 63;
  int h  = (idx >> 9) & 1;
  int kt = (idx >> 10) & 3;
  int cg = (idx >> 12) & 31;
  int p  = idx >> 17;
  int ch2 = cg * 16 + (lane & 15);
  int kk  = (kt * 8 + h * 4 + (lane >> 4)) * 8 + kk8;
  Wt[idx] = f2bf(W[(size_t)kk * 3072 + (ch2 >> 8) * 1536 + (ch2 & 255) * 6 + p]);
}

// -------------------------------------------------------------------------
// Fused pass A: GEMM (5 planes) + in-register per-segment affine summary.
// Block = 1 segment (32 flipped t) x 64 channels; wave wc owns 16 channels.
// NO LDS, NO barriers: A fragments are 1KB wave-contiguous global loads from
// xb (L2-resident), W fragments from fragment-ordered Wt (L2-resident).
// c2's dependence on the unknown segment-entry x2 (d0) is affine:
// B2 = B2k + G2*d0, resolved in scanB.
__global__ __launch_bounds__(256, 2) void fusedA_kernel(
    const u16* __restrict__ xb, const u16* __restrict__ Wt,
    const float* __restrict__ bias,
    float* __restrict__ A1, float* __restrict__ B1,
    float* __restrict__ A2, float* __restrict__ B2k,
    float* __restrict__ G2, float* __restrict__ X2B) {
  const int tid = threadIdx.x;
  const int lane = tid & 63;
  const int wc = tid >> 6;
  const int l15 = lane & 15, l4 = lane >> 4;
  const int s = blockIdx.x;          // segment 0..63
  const int bc = blockIdx.y;         // col-block 0..7 (64 ch2 each)
  const int dir = bc >> 2;
  const int ch2 = bc * 64 + wc * 16 + l15;
  const int fb0 = (bc * 4 + wc) * 8; // fragment base within plane

  const float bv3 = bias[1536 + ch2];
  const float bv4 = bias[2048 + ch2];

  float a1[4], b1[4], a2[4], b2[4], g2[4], x2p[4];
#pragma unroll
  for (int r = 0; r < 4; ++r) {
    a1[r] = 1.f; b1[r] = 0.f; a2[r] = 1.f; b2[r] = 0.f;
    g2[r] = 0.f; x2p[r] = 0.f;
  }

  for (int rt = 0; rt < 8; ++rt) {
    // per-timestep A base: row block ot; lane offset l4*128 covers the
    // kb sub-block, l15*8 the batch -> wave load = 1KB contiguous.
    const u16* ab0; const u16* ab1; const u16* ab2; const u16* ab3;
    {
      int tf = s * 32 + rt * 4;
      int o0 = dir ? (SL - 1 - tf) : tf;
      int o1 = dir ? (o0 - 1) : (o0 + 1);
      int o2 = dir ? (o0 - 2) : (o0 + 2);
      int o3 = dir ? (o0 - 3) : (o0 + 3);
      size_t lo = (size_t)(l4 * 128 + l15 * 8);
      ab0 = xb + ((size_t)o0 << 12) + lo;
      ab1 = xb + ((size_t)o1 << 12) + lo;
      ab2 = xb + ((size_t)o2 << 12) + lo;
      ab3 = xb + ((size_t)o3 << 12) + lo;
    }

    f32x4 acc[5][4];
#pragma unroll
    for (int p = 0; p < 5; ++p)
#pragma unroll
      for (int i = 0; i < 4; ++i) acc[p][i] = (f32x4){0.f, 0.f, 0.f, 0.f};

#pragma unroll
    for (int kt = 0; kt < 4; ++kt) {
#pragma unroll
      for (int h = 0; h < 2; ++h) {
        const int kb4 = (kt * 8 + h * 4) * 128;   // u16 offset of kb block
        bf16x8 af[4];
        af[0] = *(const bf16x8*)(ab0 + kb4);
        af[1] = *(const bf16x8*)(ab1 + kb4);
        af[2] = *(const bf16x8*)(ab2 + kb4);
        af[3] = *(const bf16x8*)(ab3 + kb4);
        const int fb = fb0 + kt * 2 + h;
#pragma unroll
        for (int p = 0; p < 5; ++p) {
          bf16x8 bfr = *(const bf16x8*)(
              Wt + (size_t)(p * 256 + fb) * 512 + lane * 8);
#pragma unroll
          for (int i = 0; i < 4; ++i)
            acc[p][i] = __builtin_amdgcn_mfma_f32_16x16x32_bf16(
                af[i], bfr, acc[p][i], 0, 0, 0);
        }
      }
    }

    const bool first = (rt == 0);
#pragma unroll
    for (int i = 0; i < 4; ++i) {
#pragma unroll
      for (int r = 0; r < 4; ++r) {
        float x1 = acc[0][i][r], x2v = acc[1][i][r], x3 = acc[2][i][r];
        float f1 = sigmoidf(acc[3][i][r] + bv3);
        float f2 = sigmoidf(acc[4][i][r] + bv4);
        a1[r] *= f1;
        b1[r] = f1 * b1[r] + (1.f - f1) * x1;
        float tmp = x3 * x2p[r];
        a2[r] *= f2;
        b2[r] = f2 * b2[r] + (1.f - f2) * tmp;
        g2[r] = (first && i == 0) ? (1.f - f2) * x3 : g2[r] * f2;
        x2p[r] = x2v;
      }
    }
  }

  const int chb = (l4 * 4) * 512 + ch2;  // ch = (l4*4+r)*512 + ch2
  const size_t o = (size_t)s * NCH + chb;
#pragma unroll
  for (int r = 0; r < 4; ++r) {
    size_t oo = o + (size_t)r * 512;
    A1[oo] = a1[r]; B1[oo] = b1[r]; A2[oo] = a2[r];
    B2k[oo] = b2[r]; G2[oo] = g2[r]; X2B[oo] = x2p[r];
  }
}

// -------------------------------------------------------------------------
// Pass B: compose the 64 segment maps per channel -> carry-in per segment,
// applying c2's d0-correction (B2 = B2k + G2*d0). Also final states.
__global__ __launch_bounds__(256) void scanB_kernel(
    const float* __restrict__ A1, const float* __restrict__ B1,
    const float* __restrict__ A2, const float* __restrict__ B2k,
    const float* __restrict__ G2, const float* __restrict__ X2B,
    const float* __restrict__ c1_init, const float* __restrict__ c2_init,
    const float* __restrict__ d_init,
    float* __restrict__ C1c, float* __restrict__ C2c,
    float* __restrict__ out) {
  int ch = blockIdx.x * 256 + threadIdx.x;  // < 8192
  float c1 = c1_init[ch], c2 = c2_init[ch], d0 = d_init[ch];
#pragma unroll 8
  for (int s = 0; s < SEGS; ++s) {
    int o = s * NCH + ch;
    C1c[o] = c1; C2c[o] = c2;
    c1 = A1[o] * c1 + B1[o];
    c2 = A2[o] * c2 + (B2k[o] + G2[o] * d0);
    d0 = X2B[o];
  }
  out[OFF_C1F + ch] = c1;
  out[OFF_C2F + ch] = c2;
  out[OFF_DF + ch] = d0;   // x2 at flipped t=2047
}

// -------------------------------------------------------------------------
// Fused pass C: GEMM recompute + replay with known carries; writes c1s/c2s
// f32 directly to out (un-flip dir=1 on store). Same streaming structure.
__global__ __launch_bounds__(256, 2) void fusedC_kernel(
    const u16* __restrict__ xb, const u16* __restrict__ Wt,
    const float* __restrict__ bias, const float* __restrict__ d_init,
    const float* __restrict__ X2B,
    const float* __restrict__ C1c, const float* __restrict__ C2c,
    float* __restrict__ out) {
  const int tid = threadIdx.x;
  const int lane = tid & 63;
  const int wc = tid >> 6;
  const int l15 = lane & 15, l4 = lane >> 4;
  const int s = blockIdx.x;
  const int bc = blockIdx.y;
  const int dir = bc >> 2;
  const int ch2 = bc * 64 + wc * 16 + l15;
  const int fb0 = (bc * 4 + wc) * 8;

  const float bv3 = bias[1536 + ch2];
  const float bv4 = bias[2048 + ch2];

  const int chb = (l4 * 4) * 512 + ch2;
  float c1[4], c2[4], x2p[4];
  {
    size_t o = (size_t)s * NCH + chb;
#pragma unroll
    for (int r = 0; r < 4; ++r) {
      c1[r] = C1c[o + r * 512];
      c2[r] = C2c[o + r * 512];
      x2p[r] = (s == 0) ? d_init[chb + r * 512] : X2B[o - NCH + r * 512];
    }
  }

  for (int rt = 0; rt < 8; ++rt) {
    const u16* ab0; const u16* ab1; const u16* ab2; const u16* ab3;
    {
      int tf = s * 32 + rt * 4;
      int o0 = dir ? (SL - 1 - tf) : tf;
      int o1 = dir ? (o0 - 1) : (o0 + 1);
      int o2 = dir ? (o0 - 2) : (o0 + 2);
      int o3 = dir ? (o0 - 3) : (o0 + 3);
      size_t lo = (size_t)(l4 * 128 + l15 * 8);
      ab0 = xb + ((size_t)o0 << 12) + lo;
      ab1 = xb + ((size_t)o1 << 12) + lo;
      ab2 = xb + ((size_t)o2 << 12) + lo;
      ab3 = xb + ((size_t)o3 << 12) + lo;
    }

    f32x4 acc[5][4];
#pragma unroll
    for (int p = 0; p < 5; ++p)
#pragma unroll
      for (int i = 0; i < 4; ++i) acc[p][i] = (f32x4){0.f, 0.f, 0.f, 0.f};

#pragma unroll
    for (int kt = 0; kt < 4; ++kt) {
#pragma unroll
      for (int h = 0; h < 2; ++h) {
        const int kb4 = (kt * 8 + h * 4) * 128;
        bf16x8 af[4];
        af[0] = *(const bf16x8*)(ab0 + kb4);
        af[1] = *(const bf16x8*)(ab1 + kb4);
        af[2] = *(const bf16x8*)(ab2 + kb4);
        af[3] = *(const bf16x8*)(ab3 + kb4);
        const int fb = fb0 + kt * 2 + h;
#pragma unroll
        for (int p = 0; p < 5; ++p) {
          bf16x8 bfr = *(const bf16x8*)(
              Wt + (size_t)(p * 256 + fb) * 512 + lane * 8);
#pragma unroll
          for (int i = 0; i < 4; ++i)
            acc[p][i] = __builtin_amdgcn_mfma_f32_16x16x32_bf16(
                af[i], bfr, acc[p][i], 0, 0, 0);
        }
      }
    }

#pragma unroll
    for (int i = 0; i < 4; ++i) {
      int tfl = s * 32 + rt * 4 + i;
      int t_out = dir ? (SL - 1 - tfl) : tfl;
      float* orow = out + (size_t)t_out * NCH + chb;
#pragma unroll
      for (int r = 0; r < 4; ++r) {
        float x1 = acc[0][i][r], x2v = acc[1][i][r], x3 = acc[2][i][r];
        float f1 = sigmoidf(acc[3][i][r] + bv3);
        float f2 = sigmoidf(acc[4][i][r] + bv4);
        c1[r] = f1 * c1[r] + (1.f - f1) * x1;
        float tmp = x3 * x2p[r];
        c2[r] = f2 * c2[r] + (1.f - f2) * tmp;
        x2p[r] = x2v;
        __builtin_nontemporal_store(c1[r], orow + r * 512);
        __builtin_nontemporal_store(c2[r], orow + OFF_C2S + (size_t)r * 512);
      }
    }
  }
}

// -------------------------------------------------------------------------
extern "C" void kernel_launch(void* const* d_in, const int* in_sizes, int n_in,
                              void* d_out, int out_size, void* d_ws, size_t ws_size,
                              hipStream_t stream) {
  const float* x    = (const float*)d_in[0];   // (2048,16,256) f32
  const float* W    = (const float*)d_in[1];   // (256,3072) f32
  const float* bias = (const float*)d_in[2];   // (3072,) f32
  const float* c1i  = (const float*)d_in[3];   // (16,512) f32
  const float* c2i  = (const float*)d_in[4];
  const float* di   = (const float*)d_in[5];
  float* out = (float*)d_out;                  // f32 output

  uint8_t* w8 = (uint8_t*)d_ws;
  u16* Wt  = (u16*)w8;                         // 1,310,720 B
  u16* xb  = (u16*)(w8 + 1310720ull);          // 16,777,216 B
  float* X2B = (float*)(w8 + 18087936ull);     // 2,097,152 B
  float* A1  = (float*)(w8 + 20185088ull);     // 7 x 2,097,152 B
  float* B1  = A1  + SEGS * NCH;
  float* A2  = B1  + SEGS * NCH;
  float* B2k = A2  + SEGS * NCH;
  float* G2  = B2k + SEGS * NCH;
  float* C1c = G2  + SEGS * NCH;
  float* C2c = C1c + SEGS * NCH;
  // total workspace use: ~34.9 MB (ws >= ~183 MB established in prior rounds)

  hipLaunchKernelGGL(xconv_kernel, dim3(4096), dim3(256), 0, stream, x, xb);
  hipLaunchKernelGGL(repack_kernel, dim3(2560), dim3(256), 0, stream, W, Wt);
  hipLaunchKernelGGL(fusedA_kernel, dim3(64, 8), dim3(256), 0, stream,
                     xb, Wt, bias, A1, B1, A2, B2k, G2, X2B);
  hipLaunchKernelGGL(scanB_kernel, dim3(32), dim3(256), 0, stream,
                     A1, B1, A2, B2k, G2, X2B, c1i, c2i, di, C1c, C2c, out);
  hipLaunchKernelGGL(fusedC_kernel, dim3(64, 8), dim3(256), 0, stream,
                     xb, Wt, bias, di, X2B, C1c, C2c, out);
}

// Round 5
// 363.259 us; speedup vs baseline: 1.0193x; 1.0193x over previous
//
#include <hip/hip_runtime.h>
#include <cstdint>
#include <cstddef>

typedef unsigned short u16;
typedef unsigned int u32;
typedef __bf16 bf16x8 __attribute__((ext_vector_type(8)));
typedef float f32x4 __attribute__((ext_vector_type(4)));

#define SL 2048            // sequence length
#define NCH 8192           // B(16) * BIDIR(2) * N_OUT(256)
#define SEGS 64

// out buffer element offsets (f32 output)
#define OFF_C2S 16777216
#define OFF_C1F 33554432
#define OFF_C2F 33562624
#define OFF_DF  33570816

__device__ __forceinline__ u16 f2bf(float f) {
  union { float f; u32 i; } v; v.f = f;
  u32 x = v.i;
  return (u16)((x + 0x7fffu + ((x >> 16) & 1u)) >> 16);
}
// pack two f32 -> two bf16 (RNE), 1 VALU op
__device__ __forceinline__ u32 cvtpk(float lo, float hi) {
  u32 r;
  asm("v_cvt_pk_bf16_f32 %0, %1, %2" : "=v"(r) : "v"(lo), "v"(hi));
  return r;
}
__device__ __forceinline__ float sigmoidf(float v) {
  return 1.f / (1.f + __expf(-v));
}

// -------------------------------------------------------------------------
// Convert x (f32 [t][b][256]) -> xb (bf16, layout [ot][kb(32)][b(16)][8]).
// Thread order (b inner, kb mid, ot outer): writes are 16B-contiguous per
// lane (4KB per wave); reads cover full 128B line segments.
__global__ __launch_bounds__(256) void xconv_kernel(
    const float* __restrict__ x, u16* __restrict__ xb) {
  int t8 = blockIdx.x * 256 + threadIdx.x;    // < 1,048,576
  int b  = t8 & 15;
  int kb = (t8 >> 4) & 31;
  int ot = t8 >> 9;
  const float* src = x + (((size_t)(ot * 16 + b)) << 8) + kb * 8;
  f32x4 a = *(const f32x4*)src;
  f32x4 c = *(const f32x4*)(src + 4);
  union { bf16x8 v; u32 u[4]; } h;
  h.u[0] = cvtpk(a[0], a[1]);
  h.u[1] = cvtpk(a[2], a[3]);
  h.u[2] = cvtpk(c[0], c[1]);
  h.u[3] = cvtpk(c[2], c[3]);
  *(bf16x8*)(xb + ((size_t)ot << 12) + kb * 128 + b * 8) = h.v;
}

// -------------------------------------------------------------------------
// Repack weight_in (f32, 256 x 3072) into MFMA-fragment-ordered bf16 Wt.
// Read-coalesced (col inner); scatter 2B writes land in L2-resident 1.3MB.
// Fragment f = p*256 + cg*8 + kt*2 + h holds at [lane][kk8]:
//   ch2 = cg*16 + (lane&15), kk = (kt*8 + h*4 + (lane>>4))*8 + kk8.
__global__ __launch_bounds__(256) void repack_kernel(
    const float* __restrict__ W, u16* __restrict__ Wt) {
  int idx = blockIdx.x * 256 + threadIdx.x;   // < 256*3072 = 786432
  int col = idx % 3072;
  int kk  = idx / 3072;
  float w = W[idx];                            // coalesced
  int d    = (col >= 1536) ? 1 : 0;
  int col2 = col - d * 1536;
  int n = col2 / 6;
  int p = col2 - n * 6;
  if (p >= 5) return;                          // selfloop plane unused
  int ch2 = d * 256 + n;
  int cg = ch2 >> 4, l15 = ch2 & 15;
  int kk8 = kk & 7, q = kk >> 3;
  int l4 = q & 3, h = (q >> 2) & 1, kt = q >> 3;
  size_t dst = ((size_t)(p * 256 + cg * 8 + kt * 2 + h)) * 512 +
               (l4 * 16 + l15) * 8 + kk8;
  Wt[dst] = f2bf(w);
}

// -------------------------------------------------------------------------
// Fused pass A: GEMM (5 planes) + in-register per-segment affine summary.
// Block = 1 segment (32 flipped t) x 64 channels; wave wc owns 16 channels.
// No LDS, no barriers. XCD-aware swizzle: each XCD works 8 segments ->
// 2MB xb slice + 1.3MB Wt resident in its 4MB L2.
// Summary layout [s][ch2(512)][b(16)] -> f32x4 stores (1KB/wave contiguous).
// c2's dependence on unknown segment-entry x2 (d0) is affine:
// B2 = B2k + G2*d0, resolved in scanB.
__global__ __launch_bounds__(256, 2) void fusedA_kernel(
    const u16* __restrict__ xb, const u16* __restrict__ Wt,
    const float* __restrict__ bias,
    float* __restrict__ A1, float* __restrict__ B1,
    float* __restrict__ A2, float* __restrict__ B2k,
    float* __restrict__ G2, float* __restrict__ X2B) {
  const int tid = threadIdx.x;
  const int lane = tid & 63;
  const int wc = tid >> 6;
  const int l15 = lane & 15, l4 = lane >> 4;
  const int bid = blockIdx.x;        // 0..511
  const int xcd = bid & 7;
  const int j = bid >> 3;            // 0..63
  const int s = xcd * 8 + (j & 7);   // segment 0..63 (XCD-grouped)
  const int bc = j >> 3;             // col-block 0..7 (64 ch2 each)
  const int dir = bc >> 2;
  const int ch2 = bc * 64 + wc * 16 + l15;
  const int fb0 = (bc * 4 + wc) * 8; // fragment base within plane

  const float bv3 = bias[1536 + ch2];
  const float bv4 = bias[2048 + ch2];

  float a1[4], b1[4], a2[4], b2[4], g2[4], x2p[4];
#pragma unroll
  for (int r = 0; r < 4; ++r) {
    a1[r] = 1.f; b1[r] = 0.f; a2[r] = 1.f; b2[r] = 0.f;
    g2[r] = 0.f; x2p[r] = 0.f;
  }

  for (int rt = 0; rt < 8; ++rt) {
    const u16* ab0; const u16* ab1; const u16* ab2; const u16* ab3;
    {
      int tf = s * 32 + rt * 4;
      int o0 = dir ? (SL - 1 - tf) : tf;
      int o1 = dir ? (o0 - 1) : (o0 + 1);
      int o2 = dir ? (o0 - 2) : (o0 + 2);
      int o3 = dir ? (o0 - 3) : (o0 + 3);
      size_t lo = (size_t)(l4 * 128 + l15 * 8);
      ab0 = xb + ((size_t)o0 << 12) + lo;
      ab1 = xb + ((size_t)o1 << 12) + lo;
      ab2 = xb + ((size_t)o2 << 12) + lo;
      ab3 = xb + ((size_t)o3 << 12) + lo;
    }

    f32x4 acc[5][4];
#pragma unroll
    for (int p = 0; p < 5; ++p)
#pragma unroll
      for (int i = 0; i < 4; ++i) acc[p][i] = (f32x4){0.f, 0.f, 0.f, 0.f};

#pragma unroll
    for (int kt = 0; kt < 4; ++kt) {
#pragma unroll
      for (int h = 0; h < 2; ++h) {
        const int kb4 = (kt * 8 + h * 4) * 128;   // u16 offset of kb block
        bf16x8 af[4];
        af[0] = *(const bf16x8*)(ab0 + kb4);
        af[1] = *(const bf16x8*)(ab1 + kb4);
        af[2] = *(const bf16x8*)(ab2 + kb4);
        af[3] = *(const bf16x8*)(ab3 + kb4);
        const int fb = fb0 + kt * 2 + h;
#pragma unroll
        for (int p = 0; p < 5; ++p) {
          bf16x8 bfr = *(const bf16x8*)(
              Wt + (size_t)(p * 256 + fb) * 512 + lane * 8);
#pragma unroll
          for (int i = 0; i < 4; ++i)
            acc[p][i] = __builtin_amdgcn_mfma_f32_16x16x32_bf16(
                af[i], bfr, acc[p][i], 0, 0, 0);
        }
      }
    }

    const bool first = (rt == 0);
#pragma unroll
    for (int i = 0; i < 4; ++i) {
#pragma unroll
      for (int r = 0; r < 4; ++r) {
        float x1 = acc[0][i][r], x2v = acc[1][i][r], x3 = acc[2][i][r];
        float f1 = sigmoidf(acc[3][i][r] + bv3);
        float f2 = sigmoidf(acc[4][i][r] + bv4);
        a1[r] *= f1;
        b1[r] = f1 * b1[r] + (1.f - f1) * x1;
        float tmp = x3 * x2p[r];
        a2[r] *= f2;
        b2[r] = f2 * b2[r] + (1.f - f2) * tmp;
        g2[r] = (first && i == 0) ? (1.f - f2) * x3 : g2[r] * f2;
        x2p[r] = x2v;
      }
    }
  }

  // summaries: [s][ch2][b], thread's r = consecutive b -> f32x4 stores
  const size_t oo = (size_t)s * NCH + (size_t)ch2 * 16 + l4 * 4;
  *(f32x4*)(A1  + oo) = (f32x4){a1[0], a1[1], a1[2], a1[3]};
  *(f32x4*)(B1  + oo) = (f32x4){b1[0], b1[1], b1[2], b1[3]};
  *(f32x4*)(A2  + oo) = (f32x4){a2[0], a2[1], a2[2], a2[3]};
  *(f32x4*)(B2k + oo) = (f32x4){b2[0], b2[1], b2[2], b2[3]};
  *(f32x4*)(G2  + oo) = (f32x4){g2[0], g2[1], g2[2], g2[3]};
  *(f32x4*)(X2B + oo) = (f32x4){x2p[0], x2p[1], x2p[2], x2p[3]};
}

// -------------------------------------------------------------------------
// Pass B: compose the 64 segment maps per channel -> carry-in per segment,
// applying c2's d0-correction (B2 = B2k + G2*d0). Also final states.
// Summary/carry arrays use [s][ch2][b] layout (t = ch2*16 + b).
__global__ __launch_bounds__(256) void scanB_kernel(
    const float* __restrict__ A1, const float* __restrict__ B1,
    const float* __restrict__ A2, const float* __restrict__ B2k,
    const float* __restrict__ G2, const float* __restrict__ X2B,
    const float* __restrict__ c1_init, const float* __restrict__ c2_init,
    const float* __restrict__ d_init,
    float* __restrict__ C1c, float* __restrict__ C2c,
    float* __restrict__ out) {
  int t = blockIdx.x * 256 + threadIdx.x;  // < 8192, = ch2*16 + b
  int ch2 = t >> 4, b = t & 15;
  int ch = b * 512 + ch2;                  // real channel index
  float c1 = c1_init[ch], c2 = c2_init[ch], d0 = d_init[ch];
#pragma unroll 8
  for (int s = 0; s < SEGS; ++s) {
    int o = s * NCH + t;
    C1c[o] = c1; C2c[o] = c2;
    c1 = A1[o] * c1 + B1[o];
    c2 = A2[o] * c2 + (B2k[o] + G2[o] * d0);
    d0 = X2B[o];
  }
  out[OFF_C1F + ch] = c1;
  out[OFF_C2F + ch] = c2;
  out[OFF_DF + ch] = d0;   // x2 at flipped t=2047
}

// -------------------------------------------------------------------------
// Fused pass C: GEMM recompute + replay with known carries; writes c1s/c2s
// f32 directly to out (un-flip dir=1 on store). Same swizzle as fusedA.
// NT stores keep the 134MB out stream from thrashing the XCD's L2 slice.
__global__ __launch_bounds__(256, 2) void fusedC_kernel(
    const u16* __restrict__ xb, const u16* __restrict__ Wt,
    const float* __restrict__ bias, const float* __restrict__ d_init,
    const float* __restrict__ X2B,
    const float* __restrict__ C1c, const float* __restrict__ C2c,
    float* __restrict__ out) {
  const int tid = threadIdx.x;
  const int lane = tid & 63;
  const int wc = tid >> 6;
  const int l15 = lane & 15, l4 = lane >> 4;
  const int bid = blockIdx.x;
  const int xcd = bid & 7;
  const int j = bid >> 3;
  const int s = xcd * 8 + (j & 7);
  const int bc = j >> 3;
  const int dir = bc >> 2;
  const int ch2 = bc * 64 + wc * 16 + l15;
  const int fb0 = (bc * 4 + wc) * 8;

  const float bv3 = bias[1536 + ch2];
  const float bv4 = bias[2048 + ch2];

  const int chb = (l4 * 4) * 512 + ch2;   // real ch of r=0
  float c1[4], c2[4], x2p[4];
  {
    const size_t oo = (size_t)s * NCH + (size_t)ch2 * 16 + l4 * 4;
    f32x4 u0 = *(const f32x4*)(C1c + oo);
    f32x4 w0 = *(const f32x4*)(C2c + oo);
#pragma unroll
    for (int r = 0; r < 4; ++r) { c1[r] = u0[r]; c2[r] = w0[r]; }
    if (s == 0) {
#pragma unroll
      for (int r = 0; r < 4; ++r) x2p[r] = d_init[chb + r * 512];
    } else {
      f32x4 xv = *(const f32x4*)(X2B + oo - NCH);
#pragma unroll
      for (int r = 0; r < 4; ++r) x2p[r] = xv[r];
    }
  }

  for (int rt = 0; rt < 8; ++rt) {
    const u16* ab0; const u16* ab1; const u16* ab2; const u16* ab3;
    {
      int tf = s * 32 + rt * 4;
      int o0 = dir ? (SL - 1 - tf) : tf;
      int o1 = dir ? (o0 - 1) : (o0 + 1);
      int o2 = dir ? (o0 - 2) : (o0 + 2);
      int o3 = dir ? (o0 - 3) : (o0 + 3);
      size_t lo = (size_t)(l4 * 128 + l15 * 8);
      ab0 = xb + ((size_t)o0 << 12) + lo;
      ab1 = xb + ((size_t)o1 << 12) + lo;
      ab2 = xb + ((size_t)o2 << 12) + lo;
      ab3 = xb + ((size_t)o3 << 12) + lo;
    }

    f32x4 acc[5][4];
#pragma unroll
    for (int p = 0; p < 5; ++p)
#pragma unroll
      for (int i = 0; i < 4; ++i) acc[p][i] = (f32x4){0.f, 0.f, 0.f, 0.f};

#pragma unroll
    for (int kt = 0; kt < 4; ++kt) {
#pragma unroll
      for (int h = 0; h < 2; ++h) {
        const int kb4 = (kt * 8 + h * 4) * 128;
        bf16x8 af[4];
        af[0] = *(const bf16x8*)(ab0 + kb4);
        af[1] = *(const bf16x8*)(ab1 + kb4);
        af[2] = *(const bf16x8*)(ab2 + kb4);
        af[3] = *(const bf16x8*)(ab3 + kb4);
        const int fb = fb0 + kt * 2 + h;
#pragma unroll
        for (int p = 0; p < 5; ++p) {
          bf16x8 bfr = *(const bf16x8*)(
              Wt + (size_t)(p * 256 + fb) * 512 + lane * 8);
#pragma unroll
          for (int i = 0; i < 4; ++i)
            acc[p][i] = __builtin_amdgcn_mfma_f32_16x16x32_bf16(
                af[i], bfr, acc[p][i], 0, 0, 0);
        }
      }
    }

#pragma unroll
    for (int i = 0; i < 4; ++i) {
      int tfl = s * 32 + rt * 4 + i;
      int t_out = dir ? (SL - 1 - tfl) : tfl;
      float* orow = out + (size_t)t_out * NCH + chb;
#pragma unroll
      for (int r = 0; r < 4; ++r) {
        float x1 = acc[0][i][r], x2v = acc[1][i][r], x3 = acc[2][i][r];
        float f1 = sigmoidf(acc[3][i][r] + bv3);
        float f2 = sigmoidf(acc[4][i][r] + bv4);
        c1[r] = f1 * c1[r] + (1.f - f1) * x1;
        float tmp = x3 * x2p[r];
        c2[r] = f2 * c2[r] + (1.f - f2) * tmp;
        x2p[r] = x2v;
        __builtin_nontemporal_store(c1[r], orow + r * 512);
        __builtin_nontemporal_store(c2[r], orow + OFF_C2S + (size_t)r * 512);
      }
    }
  }
}

// -------------------------------------------------------------------------
extern "C" void kernel_launch(void* const* d_in, const int* in_sizes, int n_in,
                              void* d_out, int out_size, void* d_ws, size_t ws_size,
                              hipStream_t stream) {
  const float* x    = (const float*)d_in[0];   // (2048,16,256) f32
  const float* W    = (const float*)d_in[1];   // (256,3072) f32
  const float* bias = (const float*)d_in[2];   // (3072,) f32
  const float* c1i  = (const float*)d_in[3];   // (16,512) f32
  const float* c2i  = (const float*)d_in[4];
  const float* di   = (const float*)d_in[5];
  float* out = (float*)d_out;                  // f32 output

  uint8_t* w8 = (uint8_t*)d_ws;
  u16* Wt  = (u16*)w8;                         // 1,310,720 B
  u16* xb  = (u16*)(w8 + 1310720ull);          // 16,777,216 B
  float* X2B = (float*)(w8 + 18087936ull);     // 2,097,152 B
  float* A1  = (float*)(w8 + 20185088ull);     // 7 x 2,097,152 B
  float* B1  = A1  + SEGS * NCH;
  float* A2  = B1  + SEGS * NCH;
  float* B2k = A2  + SEGS * NCH;
  float* G2  = B2k + SEGS * NCH;
  float* C1c = G2  + SEGS * NCH;
  float* C2c = C1c + SEGS * NCH;
  // total workspace use: ~34.9 MB

  hipLaunchKernelGGL(xconv_kernel, dim3(4096), dim3(256), 0, stream, x, xb);
  hipLaunchKernelGGL(repack_kernel, dim3(3072), dim3(256), 0, stream, W, Wt);
  hipLaunchKernelGGL(fusedA_kernel, dim3(512), dim3(256), 0, stream,
                     xb, Wt, bias, A1, B1, A2, B2k, G2, X2B);
  hipLaunchKernelGGL(scanB_kernel, dim3(32), dim3(256), 0, stream,
                     A1, B1, A2, B2k, G2, X2B, c1i, c2i, di, C1c, C2c, out);
  hipLaunchKernelGGL(fusedC_kernel, dim3(512), dim3(256), 0, stream,
                     xb, Wt, bias, di, X2B, C1c, C2c, out);
}